// Round 1
// baseline (225.836 us; speedup 1.0000x reference)
//
#include <hip/hip_runtime.h>

// Problem constants (match reference): B=8, H=32, T=2048, D=128, S=512, fp32.
// N = B*H*T*D = 2^26 floats per cache. All power-of-two -> shift/mask indexing.
constexpr int B = 8;
constexpr int H = 32;
constexpr int T = 2048;
constexpr int D = 128;
constexpr int S = 512;
constexpr long long N  = (long long)B * H * T * D;   // 67,108,864 floats
constexpr long long N4 = N / 4;                      // float4 count per cache

// Fused append: out[0:N) = k_new, out[N:2N) = v_new.
// For each float4 slot i (within one cache), row t=(i>>5)&2047, batch b=i>>21.
// If pos[b] <= t < pos[b]+S, source is val tensor; else the original cache.
__global__ __launch_bounds__(256) void kv_append_kernel(
    const float4* __restrict__ kc, const float4* __restrict__ vc,
    const int*    __restrict__ pos,
    const float4* __restrict__ kv, const float4* __restrict__ vv,
    float4*       __restrict__ out)
{
    __shared__ int spos[B];
    if (threadIdx.x < B) spos[threadIdx.x] = pos[threadIdx.x];
    __syncthreads();

    const long long stride = (long long)gridDim.x * blockDim.x;
    for (long long i = (long long)blockIdx.x * blockDim.x + threadIdx.x;
         i < N4; i += stride) {
        // float offset f = 4*i; decompose f = (((b*H + h)*T + t)*D + d)
        const int t = (int)((i >> 5) & (T - 1));   // (f>>7) & 2047
        const int b = (int)(i >> 21);              // f >> 23
        const int s = t - spos[b];

        float4 kr, vr;
        if ((unsigned)s < (unsigned)S) {
            // val float4 index: (((b*H+h)*S + s)*D + d) / 4
            const int h        = (int)((i >> 16) & (H - 1)); // (f>>18)&31
            const long long d4 = i & (D / 4 - 1);            // (f&127)/4
            const long long vi = ((((long long)b * H + h) * S + s) * (D / 4)) + d4;
            kr = kv[vi];
            vr = vv[vi];
        } else {
            kr = kc[i];
            vr = vc[i];
        }
        out[i]      = kr;
        out[N4 + i] = vr;
    }
}

// new_pos (output 2): B float values at the tail of d_out.
__global__ void kv_pos_kernel(const int* __restrict__ pos, float* __restrict__ out_pos)
{
    const int b = threadIdx.x;
    if (b < B) out_pos[b] = (float)(pos[b] + S);
}

extern "C" void kernel_launch(void* const* d_in, const int* in_sizes, int n_in,
                              void* d_out, int out_size, void* d_ws, size_t ws_size,
                              hipStream_t stream) {
    (void)in_sizes; (void)n_in; (void)d_ws; (void)ws_size; (void)out_size;

    const float4* kc  = (const float4*)d_in[0];  // k_cache [B,H,T,D]
    const float4* vc  = (const float4*)d_in[1];  // v_cache [B,H,T,D]
    const int*    pos = (const int*)  d_in[2];   // current_pos [B]
    const float4* kv  = (const float4*)d_in[3];  // k_val [B,H,S,D]
    const float4* vv  = (const float4*)d_in[4];  // v_val [B,H,S,D]

    float4* out = (float4*)d_out;

    // Memory-bound: grid-stride, 4096 blocks x 256 threads -> 16 float4/thread.
    dim3 grid(4096), block(256);
    kv_append_kernel<<<grid, block, 0, stream>>>(kc, vc, pos, kv, vv, out);

    float* out_pos = (float*)d_out + 2 * N;      // tail: B elements
    kv_pos_kernel<<<1, 64, 0, stream>>>(pos, out_pos);
}

// Round 2
// 203.168 us; speedup vs baseline: 1.1116x; 1.1116x over previous
//
#include <hip/hip_runtime.h>

// Problem constants (match reference): B=8, H=32, T=2048, D=128, S=512, fp32.
// N = B*H*T*D = 2^26 floats per cache. All power-of-two -> shift/mask indexing.
constexpr int B = 8;
constexpr int H = 32;
constexpr int T = 2048;
constexpr int D = 128;
constexpr int S = 512;
constexpr long long N  = (long long)B * H * T * D;   // 67,108,864 floats
constexpr long long N4 = N / 4;                      // 16,777,216 float4 per cache

typedef float f4 __attribute__((ext_vector_type(4)));

// Each block owns a contiguous CHUNK of float4 slots -> b,h are block-uniform
// (T*D/4 = 65536 float4 per (b,h); CHUNK=4096 divides it). pos[b] is a single
// scalar load; no LDS, no per-iteration lgkmcnt wait.
constexpr int CHUNK = 4096;                           // float4 per block
constexpr int NBLK  = (int)(N4 / CHUNK);              // 4096 blocks

__global__ __launch_bounds__(256) void kv_append_kernel(
    const f4* __restrict__ kc, const f4* __restrict__ vc,
    const int* __restrict__ pos,
    const f4* __restrict__ kv, const f4* __restrict__ vv,
    f4*       __restrict__ out)
{
    const long long base = (long long)blockIdx.x * CHUNK;
    // b = floor(i / 2^21), h = (i >> 16) & 31  (float4 units) — block-uniform.
    const int b = __builtin_amdgcn_readfirstlane((int)(base >> 21));
    const int h = __builtin_amdgcn_readfirstlane((int)((base >> 16) & (H - 1)));
    const int p = pos[b];                              // scalar (s_load) path
    const long long vbase = (((long long)b * H + h) * S) * (D / 4);

    #pragma unroll 4
    for (int it = 0; it < CHUNK / 256; ++it) {
        const long long i = base + it * 256 + threadIdx.x;
        const int t = (int)((i >> 5) & (T - 1));       // row within [0,T)
        const int s = t - p;
        const bool ins = (unsigned)s < (unsigned)S;    // inside appended slice?
        const long long d4 = i & (D / 4 - 1);
        const long long vi = vbase + (long long)s * (D / 4) + d4;

        // Pointer select (v_cndmask on address) — no divergent branch.
        const f4* ksrc = ins ? (kv + vi) : (kc + i);
        const f4* vsrc = ins ? (vv + vi) : (vc + i);

        f4 kr = __builtin_nontemporal_load(ksrc);
        f4 vr = __builtin_nontemporal_load(vsrc);
        __builtin_nontemporal_store(kr, out + i);
        __builtin_nontemporal_store(vr, out + N4 + i);
    }
}

// new_pos (output 2): B float values at the tail of d_out.
__global__ void kv_pos_kernel(const int* __restrict__ pos, float* __restrict__ out_pos)
{
    const int b = threadIdx.x;
    if (b < B) out_pos[b] = (float)(pos[b] + S);
}

extern "C" void kernel_launch(void* const* d_in, const int* in_sizes, int n_in,
                              void* d_out, int out_size, void* d_ws, size_t ws_size,
                              hipStream_t stream) {
    (void)in_sizes; (void)n_in; (void)d_ws; (void)ws_size; (void)out_size;

    const f4*  kc  = (const f4*)d_in[0];  // k_cache [B,H,T,D]
    const f4*  vc  = (const f4*)d_in[1];  // v_cache [B,H,T,D]
    const int* pos = (const int*)d_in[2]; // current_pos [B]
    const f4*  kv  = (const f4*)d_in[3];  // k_val [B,H,S,D]
    const f4*  vv  = (const f4*)d_in[4];  // v_val [B,H,S,D]

    f4* out = (f4*)d_out;

    kv_append_kernel<<<dim3(NBLK), dim3(256), 0, stream>>>(kc, vc, pos, kv, vv, out);

    float* out_pos = (float*)d_out + 2 * N;            // tail: B elements
    kv_pos_kernel<<<1, 64, 0, stream>>>(pos, out_pos);
}